// Round 6
// baseline (300.761 us; speedup 1.0000x reference)
//
#include <hip/hip_runtime.h>
#include <stdint.h>

typedef unsigned short u16;
typedef __bf16  bf16x8 __attribute__((ext_vector_type(8)));
typedef float   f32x4  __attribute__((ext_vector_type(4)));

__device__ __forceinline__ u16 f2bf(float f) {
    union { float f; unsigned u; } c; c.f = f;
    unsigned r = c.u + 0x7fffu + ((c.u >> 16) & 1u);   // RNE, finite inputs
    return (u16)(r >> 16);
}
__device__ __forceinline__ float bf2f(u16 b) {
    union { unsigned u; float f; } c; c.u = ((unsigned)b) << 16; return c.f;
}

// async 16B global->LDS. Generic LDS ptr: low 32 bits are the LDS offset on gfx9+.
__device__ __forceinline__ void g2l16(const u16* g, u16* l) {
    __builtin_amdgcn_global_load_lds(
        (__attribute__((address_space(1))) void*)(uintptr_t)g,
        (__attribute__((address_space(3))) void*)(uint32_t)(uintptr_t)l,
        16, 0, 0);
}

// ---------------------------------------------------------------------------
// NT GEMM core (bf16 in, fp32 acc): C[m,n] = sum_k A[m,k]*B[n,k]
//   (+ bias[m]) (+ wRbA[m]*svec[n] rank-1 term if EPI)
//   (* 1/(rs[n]*rs[512+n]) per-column softmax normalizers if CSCALE).
// A,B row-major bf16, ld == K. Tile TM x 128, BK=64, 256 thr = 4 waves (2x2).
// LDS XOR-swizzle: physical 16B chunk = logical ^ (row&7) -> conflict-free.
// Pure async staging on both operands (exp-in-staging measured as a net
// regression in R4 — normalizers are folded into the epilogue instead).
// ---------------------------------------------------------------------------
template <int TM, bool HAS_BIAS, bool OUT_F32, bool EPI, bool CSCALE>
__device__ __forceinline__ void gemm_core(
    const u16* __restrict__ Ab, const u16* __restrict__ Bb, void* __restrict__ C,
    const float* __restrict__ bias, int N, int K, long cbase, int m0, int n0,
    const float* __restrict__ svec, const float* __restrict__ wRbA,
    const float* __restrict__ rs)
{
    constexpr int MI = TM / 32;
    constexpr int NA = TM / 32;
    __shared__ __align__(16) u16 As[TM * 64];
    __shared__ __align__(16) u16 Bs[128 * 64];

    const int t = threadIdx.x;
    const int w = t >> 6, lane = t & 63;
    const int wr = w >> 1, wc = w & 1;

    f32x4 acc[MI][4];
    const f32x4 zero = {0.f, 0.f, 0.f, 0.f};
#pragma unroll
    for (int i = 0; i < MI; ++i)
#pragma unroll
        for (int j = 0; j < 4; ++j) acc[i][j] = zero;

    int  aslot[NA]; long aoff[NA];
#pragma unroll
    for (int i = 0; i < NA; ++i) {
        const int s   = i * 256 + t;
        const int row = s >> 3;
        const int col = ((s & 7) ^ (row & 7)) * 8;
        aslot[i] = s * 8;
        aoff[i]  = (long)(m0 + row) * K + col;
    }
    int  bslot[4]; long boff[4];
#pragma unroll
    for (int i = 0; i < 4; ++i) {
        const int s   = i * 256 + t;
        const int row = s >> 3;
        const int col = ((s & 7) ^ (row & 7)) * 8;
        bslot[i] = s * 8;
        boff[i]  = (long)(n0 + row) * K + col;
    }

    const int fr = lane & 15;
    const int q  = lane >> 4;
    const int o0 = ((q ^ (fr & 7)) * 8);   // kh=0; kh=1 is o0 ^ 32
    const u16* fa = &As[(wr * (TM / 2) + fr) * 64];
    const u16* fb = &Bs[(wc * 64 + fr) * 64];

    for (int k0 = 0; k0 < K; k0 += 64) {
#pragma unroll
        for (int i = 0; i < NA; ++i) g2l16(Ab + aoff[i] + k0, &As[aslot[i]]);
#pragma unroll
        for (int i = 0; i < 4; ++i)  g2l16(Bb + boff[i] + k0, &Bs[bslot[i]]);
        __syncthreads();

#pragma unroll
        for (int kh = 0; kh < 2; ++kh) {
            const int o = o0 ^ (kh * 32);
            bf16x8 af[MI], bv[4];
#pragma unroll
            for (int mi = 0; mi < MI; ++mi) af[mi] = *(const bf16x8*)(fa + mi * 1024 + o);
#pragma unroll
            for (int ni = 0; ni < 4; ++ni)  bv[ni] = *(const bf16x8*)(fb + ni * 1024 + o);
#pragma unroll
            for (int mi = 0; mi < MI; ++mi)
#pragma unroll
                for (int ni = 0; ni < 4; ++ni)
                    acc[mi][ni] = __builtin_amdgcn_mfma_f32_16x16x32_bf16(
                        af[mi], bv[ni], acc[mi][ni], 0, 0, 0);
        }
        __syncthreads();
    }

    // C/D layout (m89-verified): col = lane&15, row = (lane>>4)*4 + reg
    const int ccol  = n0 + wc * 64 + fr;
    const int crow0 = m0 + wr * (TM / 2) + (lane >> 4) * 4;
    float se[4], sc[4];
    if (EPI) {
#pragma unroll
        for (int ni = 0; ni < 4; ++ni) se[ni] = svec[ccol + ni * 16];
    }
    if (CSCALE) {
#pragma unroll
        for (int ni = 0; ni < 4; ++ni)
            sc[ni] = 1.0f / (rs[ccol + ni * 16] * rs[512 + ccol + ni * 16]);
    }
#pragma unroll
    for (int mi = 0; mi < MI; ++mi) {
#pragma unroll
        for (int r = 0; r < 4; ++r) {
            const int row = crow0 + mi * 16 + r;
            float add = HAS_BIAS ? bias[row] : 0.f;
            float rk  = EPI ? wRbA[row] : 0.f;
#pragma unroll
            for (int ni = 0; ni < 4; ++ni) {
                float v = acc[mi][ni][r] + add;
                if (CSCALE) v *= sc[ni];
                if (EPI)    v += rk * se[ni];
                const long idx = cbase + (long)row * N + ccol + ni * 16;
                if (OUT_F32) ((float*)C)[idx] = v;
                else         ((u16*)C)[idx]   = f2bf(v);
            }
        }
    }
}

// 3D-grid variant (GEMM1): blockIdx = (n-blk, m-blk, batch)
template <int TM, bool HAS_BIAS, bool OUT_F32>
__global__ __launch_bounds__(256) void gemm_nt(
    const u16* __restrict__ A, const u16* __restrict__ B, void* __restrict__ C,
    const float* __restrict__ bias, int N, int K, long sA, long sB, long sC)
{
    const int bz = blockIdx.z;
    gemm_core<TM, HAS_BIAS, OUT_F32, false, false>(
        A + (long)bz * sA, B + (long)bz * sB, C, bias, N, K,
        (long)bz * sC, blockIdx.y * TM, blockIdx.x * 128, nullptr, nullptr, nullptr);
}

// 1D-grid XCD-swizzled variant (GEMM4 / GEMM6): batch b lands on XCD b%8
template <int TM, bool HAS_BIAS, bool OUT_F32, bool EPI, bool CSCALE>
__global__ __launch_bounds__(256) void gemm_nt_swz(
    const u16* __restrict__ A, const u16* __restrict__ B, void* __restrict__ C,
    const float* __restrict__ bias, int N, int K, long sA, long sB, long sC,
    int bxn, int bpb, const float* __restrict__ s_all,
    const float* __restrict__ wRbA, const float* __restrict__ rs_all)
{
    const int blk  = blockIdx.x;
    const int xcd  = blk & 7;
    const int slot = blk >> 3;
    const int b    = xcd + 8 * (slot / bpb);
    const int wi   = slot % bpb;
    const int bx   = wi % bxn;
    const int by   = wi / bxn;
    gemm_core<TM, HAS_BIAS, OUT_F32, EPI, CSCALE>(
        A + (long)b * sA, B + (long)b * sB, C, bias, N, K,
        (long)b * sC, by * TM, bx * 128,
        EPI ? s_all + (long)b * 1024 : nullptr, wRbA,
        CSCALE ? rs_all + (long)b * 1024 : nullptr);
}

// ---------------------------------------------------------------------------
// GEMM2 (Y = Wcat * Xt^T + bcat), 256x256 tile, 512 thr = 8 waves (2x4),
// BK=32, 4 LDS buffers (128 KiB), 2-tiles-ahead prefetch, counted vmcnt(4),
// batch-colocated XCD map (1D grid 768 = 8 XCD x 96, bijective).
// v6 NEW: fused shift-free softmax-exp epilogue. For rows >= 512 (Bm/Vm
// logits, |v| <~ 5 so exp is fp32-safe without max subtraction; softmax is
// shift-invariant) the epilogue writes exp(v) and accumulates per-row sums
// into rowsum[b][row-512] (16-lane shfl reduce + 1 atomic per row-quadrant).
// Downstream consumers fold 1/rowsum in as column scales — softmax_apply's
// whole 96 MB pass is deleted.
// ---------------------------------------------------------------------------
__global__ __launch_bounds__(512) void gemm2_y(
    const u16* __restrict__ A,      // Wcat [1536,512]
    const u16* __restrict__ B,      // Xt   [b][1024,512]
    u16* __restrict__ C,            // Y    [b][1536,1024]
    const float* __restrict__ bias, // bcat [1536]
    float* __restrict__ rowsum)     // [B][1024] pre-zeroed
{
    constexpr int K    = 512;
    constexpr int NT   = K / 32;          // 16 K-tiles
    constexpr int AREG = 256 * 32;        // u16 per operand region (8192)
    constexpr int BUFQ = 2 * AREG;        // u16 per buffer (A+B)
    __shared__ __align__(16) u16 lds[4 * BUFQ];   // 128 KiB

    const int blk  = blockIdx.x;
    const int xcd  = blk & 7;
    const int slot = blk >> 3;
    const int bz   = xcd + 8 * (slot / 24);
    const int wi   = slot % 24;
    const int m0   = (wi >> 2) * 256;     // 6 m-blocks
    const int n0   = (wi & 3) * 256;      // 4 n-blocks

    const u16* Ab = A;
    const u16* Bb = B + (long)bz * (1024 * 512);
    u16*       Cb = C + (long)bz * ((long)1536 * 1024);

    const int t    = threadIdx.x;
    const int w    = t >> 6, lane = t & 63;
    const int wr   = w >> 2, wc = w & 3;          // wave grid 2(M) x 4(N)
    const int fr   = lane & 15, q = lane >> 4;

    // ---- staging map: 1024 16B-chunks per operand per K-tile; 2/thread ----
    int  aslot[2]; long agoff[2], bgoff[2];
#pragma unroll
    for (int i = 0; i < 2; ++i) {
        const int ci  = i * 512 + t;
        const int row = ci >> 2;
        const int gc  = (ci & 3) ^ ((row >> 1) & 3);   // inverse == forward (XOR)
        aslot[i] = ci * 8;                             // linear u16 LDS slot
        agoff[i] = (long)(m0 + row) * K + gc * 8;
        bgoff[i] = (long)(n0 + row) * K + gc * 8;
    }

    // ---- fragment read offsets (u16): row*32 + chunk*8 ----
    const int rchunk = (q ^ ((fr >> 1) & 3)) * 8;
    const int abase  = (wr * 128 + fr) * 32 + rchunk;   // + mi*512
    const int bbase  = (wc * 64  + fr) * 32 + rchunk;   // + ni*512

    f32x4 acc[8][4];
    const f32x4 zero = {0.f, 0.f, 0.f, 0.f};
#pragma unroll
    for (int i = 0; i < 8; ++i)
#pragma unroll
        for (int j = 0; j < 4; ++j) acc[i][j] = zero;

    // ---- prologue: stage tiles 0 and 1 (A0,B0,A1,B1 -> 8 loads/thread) ----
#pragma unroll
    for (int i = 0; i < 2; ++i) g2l16(Ab + agoff[i],        &lds[aslot[i]]);
#pragma unroll
    for (int i = 0; i < 2; ++i) g2l16(Bb + bgoff[i],        &lds[AREG + aslot[i]]);
#pragma unroll
    for (int i = 0; i < 2; ++i) g2l16(Ab + agoff[i] + 32,   &lds[BUFQ + aslot[i]]);
#pragma unroll
    for (int i = 0; i < 2; ++i) g2l16(Bb + bgoff[i] + 32,   &lds[BUFQ + AREG + aslot[i]]);
    asm volatile("s_waitcnt vmcnt(4)" ::: "memory");   // tile 0 landed; tile 1 in flight
    __builtin_amdgcn_s_barrier();
    asm volatile("" ::: "memory");                     // no hoists above barrier

#pragma unroll
    for (int kt = 0; kt < NT; ++kt) {
        const u16* Abuf = &lds[(kt & 3) * BUFQ];           // constexpr (unrolled)
        const u16* Bbuf = Abuf + AREG;
        u16* dst = &lds[((kt + 2) & 3) * BUFQ];
        const long kg = (long)(kt + 2) * 32;

        // ---- fat region: reads + stage + MFMA, compiler-scheduled ----
        bf16x8 av[8], bv[4];
#pragma unroll
        for (int mi = 0; mi < 8; ++mi) av[mi] = *(const bf16x8*)(Abuf + abase + mi * 512);
#pragma unroll
        for (int ni = 0; ni < 4; ++ni) bv[ni] = *(const bf16x8*)(Bbuf + bbase + ni * 512);
        if (kt + 2 < NT) {                                 // constexpr (unrolled)
#pragma unroll
            for (int i = 0; i < 2; ++i) g2l16(Ab + agoff[i] + kg, dst + aslot[i]);
#pragma unroll
            for (int i = 0; i < 2; ++i) g2l16(Bb + bgoff[i] + kg, dst + AREG + aslot[i]);
        }
#pragma unroll
        for (int mi = 0; mi < 8; ++mi)
#pragma unroll
            for (int ni = 0; ni < 4; ++ni)
                acc[mi][ni] = __builtin_amdgcn_mfma_f32_16x16x32_bf16(
                    av[mi], bv[ni], acc[mi][ni], 0, 0, 0);

        // ---- tile boundary: counted wait (tile kt+1 landed; kt+2 in flight) ----
        if (kt + 1 < NT) {
            if (kt + 2 < NT) asm volatile("s_waitcnt vmcnt(4)" ::: "memory");
            else             asm volatile("s_waitcnt vmcnt(0)" ::: "memory");
            __builtin_amdgcn_s_barrier();
            asm volatile("" ::: "memory");                 // no hoists above barrier
        }
    }

    // ---- epilogue: col = lane&15, row = (lane>>4)*4 + reg ----
    // sm-blocks (m0>=512): write exp(v), accumulate row sums (shift-free
    // softmax; fp32 exp on the accumulator, i.e. BEFORE bf16 rounding).
    const int ccol  = n0 + wc * 64 + fr;
    const int crow0 = m0 + wr * 128 + q * 4;
    const bool sm = (m0 >= 512);
    float* rsb = rowsum + (long)bz * 1024;
#pragma unroll
    for (int mi = 0; mi < 8; ++mi) {
#pragma unroll
        for (int r = 0; r < 4; ++r) {
            const int row = crow0 + mi * 16 + r;
            const float add = bias[row];
            float rsum = 0.f;
#pragma unroll
            for (int ni = 0; ni < 4; ++ni) {
                float v = acc[mi][ni][r] + add;
                if (sm) { v = __expf(v); rsum += v; }
                Cb[(long)row * 1024 + ccol + ni * 16] = f2bf(v);
            }
            if (sm) {
                rsum += __shfl_xor(rsum, 1);
                rsum += __shfl_xor(rsum, 2);
                rsum += __shfl_xor(rsum, 4);
                rsum += __shfl_xor(rsum, 8);
                if (fr == 0) atomicAdd(&rsb[row - 512], rsum);
            }
        }
    }
}

// ---------------------------------------------------------------------------
// x fp32 [b,512,1024] -> Xt bf16 [b,1024,512] (cast + transpose, 64x64 tiles)
// ---------------------------------------------------------------------------
__global__ __launch_bounds__(256) void cast_transpose_x(
    const float* __restrict__ in, u16* __restrict__ out)
{
    __shared__ u16 tile[64][68];
    const int bz = blockIdx.z;
    const float* ip = in  + (long)bz * (512 * 1024);
    u16*         op = out + (long)bz * (1024 * 512);
    const int c0 = blockIdx.x * 64;
    const int r0 = blockIdx.y * 64;
    const int tx = threadIdx.x & 15;
    const int ty = threadIdx.x >> 4;
#pragma unroll
    for (int p = 0; p < 4; ++p) {
        const int row = ty + 16 * p;
        float4 v = *(const float4*)(ip + (long)(r0 + row) * 1024 + c0 + 4 * tx);
        ushort4 o;
        o.x = f2bf(v.x); o.y = f2bf(v.y); o.z = f2bf(v.z); o.w = f2bf(v.w);
        *(ushort4*)&tile[row][4 * tx] = o;
    }
    __syncthreads();
#pragma unroll
    for (int p = 0; p < 4; ++p) {
        const int orow = ty + 16 * p;
        ushort4 o;
        o.x = tile[4 * tx + 0][orow];
        o.y = tile[4 * tx + 1][orow];
        o.z = tile[4 * tx + 2][orow];
        o.w = tile[4 * tx + 3][orow];
        *(ushort4*)&op[(long)(c0 + orow) * 512 + r0 + 4 * tx] = o;
    }
}

// ---------------------------------------------------------------------------
// Ev [d,n] (exp'd Vm region of Y) -> Vt = Ev^T [n,d] per batch (plain
// transpose), PLUS weighted column-sum s[b,n] += sum_d Ev[d,n]/rowsum[512+d]
// (= colsum of the normalized attnV; s pre-zeroed).
// ---------------------------------------------------------------------------
__global__ __launch_bounds__(256) void transpose_colsum(
    const u16* __restrict__ in, u16* __restrict__ out, float* __restrict__ s,
    long sIn, long sOut, const float* __restrict__ rowsum)
{
    __shared__ u16 tile[64][68];
    __shared__ float sinv[64];
    const int bz = blockIdx.z;
    const u16* ip = in  + (long)bz * sIn;
    u16*       op = out + (long)bz * sOut;
    const int c0 = blockIdx.x * 64;   // n
    const int r0 = blockIdx.y * 64;   // d
    const int t  = threadIdx.x;
    const int tx = t & 15;
    const int ty = t >> 4;
    if (t < 64) sinv[t] = 1.0f / rowsum[(long)bz * 1024 + 512 + r0 + t];
#pragma unroll
    for (int p = 0; p < 4; ++p) {
        const int row = ty + 16 * p;
        ushort4 v = *(const ushort4*)(ip + (long)(r0 + row) * 1024 + c0 + 4 * tx);
        *(ushort4*)&tile[row][4 * tx] = v;
    }
    __syncthreads();
#pragma unroll
    for (int p = 0; p < 4; ++p) {
        const int orow = ty + 16 * p;
        ushort4 o;
        o.x = tile[4 * tx + 0][orow];
        o.y = tile[4 * tx + 1][orow];
        o.z = tile[4 * tx + 2][orow];
        o.w = tile[4 * tx + 3][orow];
        *(ushort4*)&op[(long)(c0 + orow) * 512 + r0 + 4 * tx] = o;
    }
    if (t < 64) {
        float a = 0.f;
#pragma unroll 8
        for (int d = 0; d < 64; ++d) a += bf2f(tile[d][t]) * sinv[d];
        atomicAdd(&s[(long)bz * 1024 + c0 + t], a);
    }
}

// ---------------------------------------------------------------------------
// prep_weights = weight casts + wRbA + {svec, rowsum} zero, one launch.
//  blocks 0..4102   : weight casts / bcat
//  blocks 4103..4230: wRbA[o] = sum_c wR[o,c]*bA[c]  (4 waves -> 4 o/block)
//  blocks 4231..4358: svec = 0    (32*1024 floats)
//  blocks 4359..4486: rowsum = 0  (32*1024 floats)
// ---------------------------------------------------------------------------
__global__ __launch_bounds__(256) void prep_weights(
    const float* __restrict__ wA, const float* __restrict__ wB,
    const float* __restrict__ wV, const float* __restrict__ wR,
    const float* __restrict__ bA, const float* __restrict__ bB,
    const float* __restrict__ bV,
    u16* __restrict__ Wcat, u16* __restrict__ wRb, u16* __restrict__ wAtb,
    float* __restrict__ bcat, float* __restrict__ wRbA,
    float* __restrict__ svec, float* __restrict__ rowsum)
{
    const int blk = blockIdx.x;
    if (blk < 4103) {
        const int tid = blk * 256 + threadIdx.x;
        if (tid < 262144) {
            Wcat[262144 + tid] = f2bf(wB[tid]);                    // rows 512..1023
        } else if (tid < 524288) {
            Wcat[262144 + tid] = f2bf(wV[tid - 262144]);           // rows 1024..1535
        } else if (tid < 786432) {
            wRb[tid - 524288] = f2bf(wR[tid - 524288]);
        } else if (tid < 1048576) {
            const int i = tid - 786432;                            // i = c*512 + cin
            wAtb[(i & 511) * 512 + (i >> 9)] = f2bf(wA[i]);        // wA^T
        } else if (tid < 1048576 + 1536) {
            const int j = tid - 1048576;
            bcat[j] = (j < 512) ? 0.f : (j < 1024) ? bB[j - 512] : bV[j - 1024];
        }
    } else if (blk < 4231) {
        const int o    = (blk - 4103) * 4 + (threadIdx.x >> 6);
        const int lane = threadIdx.x & 63;
        float a = 0.f;
#pragma unroll
        for (int c = lane; c < 512; c += 64) a += wR[o * 512 + c] * bA[c];
#pragma unroll
        for (int off = 32; off > 0; off >>= 1) a += __shfl_down(a, off);
        if (lane == 0) wRbA[o] = a;
    } else if (blk < 4359) {
        svec[(blk - 4231) * 256 + threadIdx.x] = 0.f;
    } else {
        rowsum[(blk - 4359) * 256 + threadIdx.x] = 0.f;
    }
}

// ---------------------------------------------------------------------------
extern "C" void kernel_launch(void* const* d_in, const int* in_sizes, int n_in,
                              void* d_out, int out_size, void* d_ws, size_t ws_size,
                              hipStream_t stream)
{
    (void)in_sizes; (void)n_in; (void)out_size; (void)ws_size;
    const float* x  = (const float*)d_in[0];
    const float* wA = (const float*)d_in[1];
    const float* bA = (const float*)d_in[2];
    const float* wB = (const float*)d_in[3];
    const float* bB = (const float*)d_in[4];
    const float* wV = (const float*)d_in[5];
    const float* bV = (const float*)d_in[6];
    const float* wR = (const float*)d_in[7];
    const float* bR = (const float*)d_in[8];
    float* out = (float*)d_out;

    const int B = 32;
    const long sY = (long)1536 * 1024;   // per-batch Y stride (bf16 elems)

    // workspace carve-up (~116 MB)
    char* p = (char*)d_ws;
    u16*   Y    = (u16*)p;   p += (long)B * sY * 2;          // 96 MB  [A'; Em; Ev]
    u16*   H    = (u16*)p;   p += (long)B * 512 * 512 * 2;   // 16 MB  H2 [o,d]
    u16*   Wcat = (u16*)p;   p += (long)1536 * 512 * 2;      // [M1;wB;wV]
    u16*   wRb  = (u16*)p;   p += (long)512 * 512 * 2;
    u16*   wAtb = (u16*)p;   p += (long)512 * 512 * 2;       // wA^T bf16
    float* bcat = (float*)p; p += 1536 * 4;
    float* svec = (float*)p; p += (long)B * 1024 * 4;        // colsum of attnV
    float* wRbA = (float*)p; p += 512 * 4;
    float* rowsum = (float*)p; p += (long)B * 1024 * 4;      // sum(exp) Bm;Vm rows

    // Xt (bf16 [b,1024,512], 33.5 MB) lives in d_out — dead before final GEMM
    u16* Xt = (u16*)d_out;
    // Vt reuses Y's A'-region after the H-GEMM consumed A'
    u16* Vt = Y;                        // [1024,512] per batch, stride sY

    // 0. casts + tiny precomputes
    cast_transpose_x<<<dim3(16, 8, B), 256, 0, stream>>>(x, Xt);
    prep_weights<<<dim3(4487), 256, 0, stream>>>(wA, wB, wV, wR, bA, bB, bV,
                                                 Wcat, wRb, wAtb, bcat, wRbA,
                                                 svec, rowsum);

    // 1. M1 = wR*wA -> Wcat rows 0..511   (NT: A=wRb[512,512], B=wAtb[512,512])
    gemm_nt<128, false, false><<<dim3(4, 4, 1), 256, 0, stream>>>(
        wRb, wAtb, Wcat, nullptr, 512, 512, 0, 0, 0);

    // 2. Y[b] = Wcat * X[b] + bcat; rows 512+ get exp() + rowsum (fused softmax)
    gemm2_y<<<dim3(768), 512, 0, stream>>>(Wcat, Xt, Y, bcat, rowsum);

    // 3. H2[b][o,d] = (sum_n A'[o,n]*Em[d,n]) / (S_b[d]*S_v[d])
    //    (NT, K=1024; pure async staging; normalizers as column scales)
    gemm_nt_swz<128, false, false, false, true><<<dim3(512), 256, 0, stream>>>(
        Y, Y + (long)512 * 1024, H, nullptr, 512, 1024,
        sY, sY, (long)512 * 512, 4, 16, nullptr, nullptr, rowsum);

    // 4. Vt[b] = Ev[b]^T; svec[n] = sum_d Ev[d,n]/S_v[d]  (A'-region dead now)
    transpose_colsum<<<dim3(16, 8, B), 256, 0, stream>>>(
        Y + (long)1024 * 1024, Vt, svec, sY, sY, rowsum);

    // 5. out[b][o,n] = sum_d H2[o,d]*Vt[n,d] + wRbA[o]*svec[n] + bR[o] (fp32)
    gemm_nt_swz<128, true, true, true, false><<<dim3(1024), 256, 0, stream>>>(
        H, Vt, out, bR, 1024, 512, (long)512 * 512, sY, (long)512 * 1024,
        8, 32, svec, wRbA, nullptr);
}

// Round 7
// 280.802 us; speedup vs baseline: 1.0711x; 1.0711x over previous
//
#include <hip/hip_runtime.h>
#include <stdint.h>

typedef unsigned short u16;
typedef __bf16  bf16x8 __attribute__((ext_vector_type(8)));
typedef float   f32x4  __attribute__((ext_vector_type(4)));

__device__ __forceinline__ u16 f2bf(float f) {
    union { float f; unsigned u; } c; c.f = f;
    unsigned r = c.u + 0x7fffu + ((c.u >> 16) & 1u);   // RNE, finite inputs
    return (u16)(r >> 16);
}
__device__ __forceinline__ float bf2f(u16 b) {
    union { unsigned u; float f; } c; c.u = ((unsigned)b) << 16; return c.f;
}

// async 16B global->LDS. Generic LDS ptr: low 32 bits are the LDS offset on gfx9+.
__device__ __forceinline__ void g2l16(const u16* g, u16* l) {
    __builtin_amdgcn_global_load_lds(
        (__attribute__((address_space(1))) void*)(uintptr_t)g,
        (__attribute__((address_space(3))) void*)(uint32_t)(uintptr_t)l,
        16, 0, 0);
}

// ---------------------------------------------------------------------------
// NT GEMM core (bf16 in, fp32 acc): C[m,n] = sum_k A[m,k]*B[n,k]
//   (+ bias[m]) (+ wRbA[m]*svec[n] rank-1 term if EPI)
//   (* 1/(S_b[n]*S_v[n]) per-column softmax normalizers if CSCALE, where
//    S_b[n] = sum of 4 rspart Bm partials, S_v[n] = same for Vm).
// A,B row-major bf16, ld == K. Tile TM x 128, BK=64, 256 thr = 4 waves (2x2).
// LDS XOR-swizzle: physical 16B chunk = logical ^ (row&7) -> conflict-free.
// ---------------------------------------------------------------------------
template <int TM, bool HAS_BIAS, bool OUT_F32, bool EPI, bool CSCALE>
__device__ __forceinline__ void gemm_core(
    const u16* __restrict__ Ab, const u16* __restrict__ Bb, void* __restrict__ C,
    const float* __restrict__ bias, int N, int K, long cbase, int m0, int n0,
    const float* __restrict__ svec, const float* __restrict__ wRbA,
    const float* __restrict__ rs)   // rspart[4][1024] for this batch
{
    constexpr int MI = TM / 32;
    constexpr int NA = TM / 32;
    __shared__ __align__(16) u16 As[TM * 64];
    __shared__ __align__(16) u16 Bs[128 * 64];

    const int t = threadIdx.x;
    const int w = t >> 6, lane = t & 63;
    const int wr = w >> 1, wc = w & 1;

    f32x4 acc[MI][4];
    const f32x4 zero = {0.f, 0.f, 0.f, 0.f};
#pragma unroll
    for (int i = 0; i < MI; ++i)
#pragma unroll
        for (int j = 0; j < 4; ++j) acc[i][j] = zero;

    int  aslot[NA]; long aoff[NA];
#pragma unroll
    for (int i = 0; i < NA; ++i) {
        const int s   = i * 256 + t;
        const int row = s >> 3;
        const int col = ((s & 7) ^ (row & 7)) * 8;
        aslot[i] = s * 8;
        aoff[i]  = (long)(m0 + row) * K + col;
    }
    int  bslot[4]; long boff[4];
#pragma unroll
    for (int i = 0; i < 4; ++i) {
        const int s   = i * 256 + t;
        const int row = s >> 3;
        const int col = ((s & 7) ^ (row & 7)) * 8;
        bslot[i] = s * 8;
        boff[i]  = (long)(n0 + row) * K + col;
    }

    const int fr = lane & 15;
    const int q  = lane >> 4;
    const int o0 = ((q ^ (fr & 7)) * 8);   // kh=0; kh=1 is o0 ^ 32
    const u16* fa = &As[(wr * (TM / 2) + fr) * 64];
    const u16* fb = &Bs[(wc * 64 + fr) * 64];

    for (int k0 = 0; k0 < K; k0 += 64) {
#pragma unroll
        for (int i = 0; i < NA; ++i) g2l16(Ab + aoff[i] + k0, &As[aslot[i]]);
#pragma unroll
        for (int i = 0; i < 4; ++i)  g2l16(Bb + boff[i] + k0, &Bs[bslot[i]]);
        __syncthreads();

#pragma unroll
        for (int kh = 0; kh < 2; ++kh) {
            const int o = o0 ^ (kh * 32);
            bf16x8 af[MI], bv[4];
#pragma unroll
            for (int mi = 0; mi < MI; ++mi) af[mi] = *(const bf16x8*)(fa + mi * 1024 + o);
#pragma unroll
            for (int ni = 0; ni < 4; ++ni)  bv[ni] = *(const bf16x8*)(fb + ni * 1024 + o);
#pragma unroll
            for (int mi = 0; mi < MI; ++mi)
#pragma unroll
                for (int ni = 0; ni < 4; ++ni)
                    acc[mi][ni] = __builtin_amdgcn_mfma_f32_16x16x32_bf16(
                        af[mi], bv[ni], acc[mi][ni], 0, 0, 0);
        }
        __syncthreads();
    }

    // C/D layout (m89-verified): col = lane&15, row = (lane>>4)*4 + reg
    const int ccol  = n0 + wc * 64 + fr;
    const int crow0 = m0 + wr * (TM / 2) + (lane >> 4) * 4;
    float se[4], sc[4];
    if (EPI) {
#pragma unroll
        for (int ni = 0; ni < 4; ++ni) se[ni] = svec[ccol + ni * 16];
    }
    if (CSCALE) {
#pragma unroll
        for (int ni = 0; ni < 4; ++ni) {
            const int c = ccol + ni * 16;
            const float sb = rs[c]       + rs[1024 + c] + rs[2048 + c] + rs[3072 + c];
            const float sv = rs[512 + c] + rs[1536 + c] + rs[2560 + c] + rs[3584 + c];
            sc[ni] = 1.0f / (sb * sv);
        }
    }
#pragma unroll
    for (int mi = 0; mi < MI; ++mi) {
#pragma unroll
        for (int r = 0; r < 4; ++r) {
            const int row = crow0 + mi * 16 + r;
            float add = HAS_BIAS ? bias[row] : 0.f;
            float rk  = EPI ? wRbA[row] : 0.f;
#pragma unroll
            for (int ni = 0; ni < 4; ++ni) {
                float v = acc[mi][ni][r] + add;
                if (CSCALE) v *= sc[ni];
                if (EPI)    v += rk * se[ni];
                const long idx = cbase + (long)row * N + ccol + ni * 16;
                if (OUT_F32) ((float*)C)[idx] = v;
                else         ((u16*)C)[idx]   = f2bf(v);
            }
        }
    }
}

// 3D-grid variant (GEMM1): blockIdx = (n-blk, m-blk, batch)
template <int TM, bool HAS_BIAS, bool OUT_F32>
__global__ __launch_bounds__(256) void gemm_nt(
    const u16* __restrict__ A, const u16* __restrict__ B, void* __restrict__ C,
    const float* __restrict__ bias, int N, int K, long sA, long sB, long sC)
{
    const int bz = blockIdx.z;
    gemm_core<TM, HAS_BIAS, OUT_F32, false, false>(
        A + (long)bz * sA, B + (long)bz * sB, C, bias, N, K,
        (long)bz * sC, blockIdx.y * TM, blockIdx.x * 128, nullptr, nullptr, nullptr);
}

// 1D-grid XCD-swizzled variant (GEMM4 / GEMM6): batch b lands on XCD b%8
template <int TM, bool HAS_BIAS, bool OUT_F32, bool EPI, bool CSCALE>
__global__ __launch_bounds__(256) void gemm_nt_swz(
    const u16* __restrict__ A, const u16* __restrict__ B, void* __restrict__ C,
    const float* __restrict__ bias, int N, int K, long sA, long sB, long sC,
    int bxn, int bpb, const float* __restrict__ s_all,
    const float* __restrict__ wRbA, const float* __restrict__ rs_all)
{
    const int blk  = blockIdx.x;
    const int xcd  = blk & 7;
    const int slot = blk >> 3;
    const int b    = xcd + 8 * (slot / bpb);
    const int wi   = slot % bpb;
    const int bx   = wi % bxn;
    const int by   = wi / bxn;
    gemm_core<TM, HAS_BIAS, OUT_F32, EPI, CSCALE>(
        A + (long)b * sA, B + (long)b * sB, C, bias, N, K,
        (long)b * sC, by * TM, bx * 128,
        EPI ? s_all + (long)b * 1024 : nullptr, wRbA,
        CSCALE ? rs_all + (long)b * 4096 : nullptr);
}

// ---------------------------------------------------------------------------
// GEMM2 (Y = Wcat * Xt^T + bcat), 256x256 tile, 512 thr = 8 waves (2x4),
// BK=32, 4 LDS buffers (128 KiB), 2-tiles-ahead prefetch, counted vmcnt(4),
// batch-colocated XCD map (1D grid 768 = 8 XCD x 96, bijective).
// v7 epilogue (fixes R6's 104 µs): shift-free softmax exp on the fp32
// accumulators for rows >= 512, per-row partial sums reduced via 4 shfls +
// LDS (reusing the staging buffers post-loop) and written with ONE PLAIN
// STORE per (row, n-block) into rspart[b][n0/256][row]. R6's global
// atomicAdd rowsum had 64-way same-address contention + 8 MB write-through
// (WRITE_SIZE 98304->106496) -> 40 µs epilogue stall. No atomics here.
// Consumers (gemm4 CSCALE, transpose_colsum) sum the 4 partials themselves.
// ---------------------------------------------------------------------------
__global__ __launch_bounds__(512) void gemm2_y(
    const u16* __restrict__ A,      // Wcat [1536,512]
    const u16* __restrict__ B,      // Xt   [b][1024,512]
    u16* __restrict__ C,            // Y    [b][1536,1024]
    const float* __restrict__ bias, // bcat [1536]
    float* __restrict__ rspart)     // [B][4][1024] partial exp-rowsums
{
    constexpr int K    = 512;
    constexpr int NT   = K / 32;          // 16 K-tiles
    constexpr int AREG = 256 * 32;        // u16 per operand region (8192)
    constexpr int BUFQ = 2 * AREG;        // u16 per buffer (A+B)
    __shared__ __align__(16) u16 lds[4 * BUFQ];   // 128 KiB

    const int blk  = blockIdx.x;
    const int xcd  = blk & 7;
    const int slot = blk >> 3;
    const int bz   = xcd + 8 * (slot / 24);
    const int wi   = slot % 24;
    const int m0   = (wi >> 2) * 256;     // 6 m-blocks
    const int n0   = (wi & 3) * 256;      // 4 n-blocks

    const u16* Ab = A;
    const u16* Bb = B + (long)bz * (1024 * 512);
    u16*       Cb = C + (long)bz * ((long)1536 * 1024);

    const int t    = threadIdx.x;
    const int w    = t >> 6, lane = t & 63;
    const int wr   = w >> 2, wc = w & 3;          // wave grid 2(M) x 4(N)
    const int fr   = lane & 15, q = lane >> 4;

    // ---- staging map: 1024 16B-chunks per operand per K-tile; 2/thread ----
    int  aslot[2]; long agoff[2], bgoff[2];
#pragma unroll
    for (int i = 0; i < 2; ++i) {
        const int ci  = i * 512 + t;
        const int row = ci >> 2;
        const int gc  = (ci & 3) ^ ((row >> 1) & 3);   // inverse == forward (XOR)
        aslot[i] = ci * 8;                             // linear u16 LDS slot
        agoff[i] = (long)(m0 + row) * K + gc * 8;
        bgoff[i] = (long)(n0 + row) * K + gc * 8;
    }

    // ---- fragment read offsets (u16): row*32 + chunk*8 ----
    const int rchunk = (q ^ ((fr >> 1) & 3)) * 8;
    const int abase  = (wr * 128 + fr) * 32 + rchunk;   // + mi*512
    const int bbase  = (wc * 64  + fr) * 32 + rchunk;   // + ni*512

    f32x4 acc[8][4];
    const f32x4 zero = {0.f, 0.f, 0.f, 0.f};
#pragma unroll
    for (int i = 0; i < 8; ++i)
#pragma unroll
        for (int j = 0; j < 4; ++j) acc[i][j] = zero;

    // ---- prologue: stage tiles 0 and 1 (A0,B0,A1,B1 -> 8 loads/thread) ----
#pragma unroll
    for (int i = 0; i < 2; ++i) g2l16(Ab + agoff[i],        &lds[aslot[i]]);
#pragma unroll
    for (int i = 0; i < 2; ++i) g2l16(Bb + bgoff[i],        &lds[AREG + aslot[i]]);
#pragma unroll
    for (int i = 0; i < 2; ++i) g2l16(Ab + agoff[i] + 32,   &lds[BUFQ + aslot[i]]);
#pragma unroll
    for (int i = 0; i < 2; ++i) g2l16(Bb + bgoff[i] + 32,   &lds[BUFQ + AREG + aslot[i]]);
    asm volatile("s_waitcnt vmcnt(4)" ::: "memory");   // tile 0 landed; tile 1 in flight
    __builtin_amdgcn_s_barrier();
    asm volatile("" ::: "memory");                     // no hoists above barrier

#pragma unroll
    for (int kt = 0; kt < NT; ++kt) {
        const u16* Abuf = &lds[(kt & 3) * BUFQ];           // constexpr (unrolled)
        const u16* Bbuf = Abuf + AREG;
        u16* dst = &lds[((kt + 2) & 3) * BUFQ];
        const long kg = (long)(kt + 2) * 32;

        // ---- fat region: reads + stage + MFMA, compiler-scheduled ----
        bf16x8 av[8], bv[4];
#pragma unroll
        for (int mi = 0; mi < 8; ++mi) av[mi] = *(const bf16x8*)(Abuf + abase + mi * 512);
#pragma unroll
        for (int ni = 0; ni < 4; ++ni) bv[ni] = *(const bf16x8*)(Bbuf + bbase + ni * 512);
        if (kt + 2 < NT) {                                 // constexpr (unrolled)
#pragma unroll
            for (int i = 0; i < 2; ++i) g2l16(Ab + agoff[i] + kg, dst + aslot[i]);
#pragma unroll
            for (int i = 0; i < 2; ++i) g2l16(Bb + bgoff[i] + kg, dst + AREG + aslot[i]);
        }
#pragma unroll
        for (int mi = 0; mi < 8; ++mi)
#pragma unroll
            for (int ni = 0; ni < 4; ++ni)
                acc[mi][ni] = __builtin_amdgcn_mfma_f32_16x16x32_bf16(
                    av[mi], bv[ni], acc[mi][ni], 0, 0, 0);

        // ---- tile boundary: counted wait (tile kt+1 landed; kt+2 in flight) ----
        if (kt + 1 < NT) {
            if (kt + 2 < NT) asm volatile("s_waitcnt vmcnt(4)" ::: "memory");
            else             asm volatile("s_waitcnt vmcnt(0)" ::: "memory");
            __builtin_amdgcn_s_barrier();
            asm volatile("" ::: "memory");                 // no hoists above barrier
        }
    }

    // ---- epilogue: col = lane&15, row = (lane>>4)*4 + reg ----
    const int ccol  = n0 + wc * 64 + fr;
    const int crow0 = m0 + wr * 128 + q * 4;
    const bool sm = (m0 >= 512);
    float rsums[8][4];
#pragma unroll
    for (int mi = 0; mi < 8; ++mi) {
#pragma unroll
        for (int r = 0; r < 4; ++r) {
            const int row = crow0 + mi * 16 + r;
            const float add = bias[row];
            float rsum = 0.f;
#pragma unroll
            for (int ni = 0; ni < 4; ++ni) {
                float v = acc[mi][ni][r] + add;
                if (sm) { v = __expf(v); rsum += v; }
                Cb[(long)row * 1024 + ccol + ni * 16] = f2bf(v);
            }
            rsums[mi][r] = rsum;
        }
    }
    if (sm) {   // uniform branch (m0 is block-uniform)
        // reduce over the 16 fr lanes -> fr==0 holds this wave's 64-col sum
#pragma unroll
        for (int mi = 0; mi < 8; ++mi)
#pragma unroll
            for (int r = 0; r < 4; ++r) {
                float v = rsums[mi][r];
                v += __shfl_xor(v, 1);
                v += __shfl_xor(v, 2);
                v += __shfl_xor(v, 4);
                v += __shfl_xor(v, 8);
                rsums[mi][r] = v;
            }
        __syncthreads();                 // all LDS reads of the K-loop done
        float* lsc = (float*)lds;        // scratch: [2][128][4] (wr, lrow, wc)
        if (fr == 0) {
#pragma unroll
            for (int mi = 0; mi < 8; ++mi)
#pragma unroll
                for (int r = 0; r < 4; ++r) {
                    const int lrow = mi * 16 + q * 4 + r;          // 0..127
                    lsc[(wr * 128 + lrow) * 4 + wc] = rsums[mi][r];
                }
        }
        __syncthreads();
        if (t < 256) {
            const f32x4 pv = *(const f32x4*)&lsc[t * 4];
            const int grow = (m0 - 512) + t;                       // 0..1023
            rspart[((long)bz * 4 + (n0 >> 8)) * 1024 + grow] =
                pv[0] + pv[1] + pv[2] + pv[3];
        }
    }
}

// ---------------------------------------------------------------------------
// x fp32 [b,512,1024] -> Xt bf16 [b,1024,512] (cast + transpose, 64x64 tiles)
// ---------------------------------------------------------------------------
__global__ __launch_bounds__(256) void cast_transpose_x(
    const float* __restrict__ in, u16* __restrict__ out)
{
    __shared__ u16 tile[64][68];
    const int bz = blockIdx.z;
    const float* ip = in  + (long)bz * (512 * 1024);
    u16*         op = out + (long)bz * (1024 * 512);
    const int c0 = blockIdx.x * 64;
    const int r0 = blockIdx.y * 64;
    const int tx = threadIdx.x & 15;
    const int ty = threadIdx.x >> 4;
#pragma unroll
    for (int p = 0; p < 4; ++p) {
        const int row = ty + 16 * p;
        float4 v = *(const float4*)(ip + (long)(r0 + row) * 1024 + c0 + 4 * tx);
        ushort4 o;
        o.x = f2bf(v.x); o.y = f2bf(v.y); o.z = f2bf(v.z); o.w = f2bf(v.w);
        *(ushort4*)&tile[row][4 * tx] = o;
    }
    __syncthreads();
#pragma unroll
    for (int p = 0; p < 4; ++p) {
        const int orow = ty + 16 * p;
        ushort4 o;
        o.x = tile[4 * tx + 0][orow];
        o.y = tile[4 * tx + 1][orow];
        o.z = tile[4 * tx + 2][orow];
        o.w = tile[4 * tx + 3][orow];
        *(ushort4*)&op[(long)(c0 + orow) * 512 + r0 + 4 * tx] = o;
    }
}

// ---------------------------------------------------------------------------
// Ev [d,n] (exp'd Vm region of Y) -> Vt = Ev^T [n,d] per batch (plain
// transpose), PLUS weighted column-sum s[b,n] += sum_d Ev[d,n]/S_v[d]
// with S_v[d] = sum of 4 rspart partials (s pre-zeroed).
// ---------------------------------------------------------------------------
__global__ __launch_bounds__(256) void transpose_colsum(
    const u16* __restrict__ in, u16* __restrict__ out, float* __restrict__ s,
    long sIn, long sOut, const float* __restrict__ rspart)
{
    __shared__ u16 tile[64][68];
    __shared__ float sinv[64];
    const int bz = blockIdx.z;
    const u16* ip = in  + (long)bz * sIn;
    u16*       op = out + (long)bz * sOut;
    const int c0 = blockIdx.x * 64;   // n
    const int r0 = blockIdx.y * 64;   // d
    const int t  = threadIdx.x;
    const int tx = t & 15;
    const int ty = t >> 4;
    if (t < 64) {
        const float* rs = rspart + (long)bz * 4096 + 512 + r0 + t;
        sinv[t] = 1.0f / (rs[0] + rs[1024] + rs[2048] + rs[3072]);
    }
#pragma unroll
    for (int p = 0; p < 4; ++p) {
        const int row = ty + 16 * p;
        ushort4 v = *(const ushort4*)(ip + (long)(r0 + row) * 1024 + c0 + 4 * tx);
        *(ushort4*)&tile[row][4 * tx] = v;
    }
    __syncthreads();
#pragma unroll
    for (int p = 0; p < 4; ++p) {
        const int orow = ty + 16 * p;
        ushort4 o;
        o.x = tile[4 * tx + 0][orow];
        o.y = tile[4 * tx + 1][orow];
        o.z = tile[4 * tx + 2][orow];
        o.w = tile[4 * tx + 3][orow];
        *(ushort4*)&op[(long)(c0 + orow) * 512 + r0 + 4 * tx] = o;
    }
    if (t < 64) {
        float a = 0.f;
#pragma unroll 8
        for (int d = 0; d < 64; ++d) a += bf2f(tile[d][t]) * sinv[d];
        atomicAdd(&s[(long)bz * 1024 + c0 + t], a);
    }
}

// ---------------------------------------------------------------------------
// prep_weights = weight casts + wRbA + svec zero, one launch.
//  blocks 0..4102   : weight casts / bcat
//  blocks 4103..4230: wRbA[o] = sum_c wR[o,c]*bA[c]  (4 waves -> 4 o/block)
//  blocks 4231..4358: svec = 0    (32*1024 floats)
// (rspart needs no zeroing: every slot written exactly once by gemm2_y)
// ---------------------------------------------------------------------------
__global__ __launch_bounds__(256) void prep_weights(
    const float* __restrict__ wA, const float* __restrict__ wB,
    const float* __restrict__ wV, const float* __restrict__ wR,
    const float* __restrict__ bA, const float* __restrict__ bB,
    const float* __restrict__ bV,
    u16* __restrict__ Wcat, u16* __restrict__ wRb, u16* __restrict__ wAtb,
    float* __restrict__ bcat, float* __restrict__ wRbA,
    float* __restrict__ svec)
{
    const int blk = blockIdx.x;
    if (blk < 4103) {
        const int tid = blk * 256 + threadIdx.x;
        if (tid < 262144) {
            Wcat[262144 + tid] = f2bf(wB[tid]);                    // rows 512..1023
        } else if (tid < 524288) {
            Wcat[262144 + tid] = f2bf(wV[tid - 262144]);           // rows 1024..1535
        } else if (tid < 786432) {
            wRb[tid - 524288] = f2bf(wR[tid - 524288]);
        } else if (tid < 1048576) {
            const int i = tid - 786432;                            // i = c*512 + cin
            wAtb[(i & 511) * 512 + (i >> 9)] = f2bf(wA[i]);        // wA^T
        } else if (tid < 1048576 + 1536) {
            const int j = tid - 1048576;
            bcat[j] = (j < 512) ? 0.f : (j < 1024) ? bB[j - 512] : bV[j - 1024];
        }
    } else if (blk < 4231) {
        const int o    = (blk - 4103) * 4 + (threadIdx.x >> 6);
        const int lane = threadIdx.x & 63;
        float a = 0.f;
#pragma unroll
        for (int c = lane; c < 512; c += 64) a += wR[o * 512 + c] * bA[c];
#pragma unroll
        for (int off = 32; off > 0; off >>= 1) a += __shfl_down(a, off);
        if (lane == 0) wRbA[o] = a;
    } else {
        svec[(blk - 4231) * 256 + threadIdx.x] = 0.f;
    }
}

// ---------------------------------------------------------------------------
extern "C" void kernel_launch(void* const* d_in, const int* in_sizes, int n_in,
                              void* d_out, int out_size, void* d_ws, size_t ws_size,
                              hipStream_t stream)
{
    (void)in_sizes; (void)n_in; (void)out_size; (void)ws_size;
    const float* x  = (const float*)d_in[0];
    const float* wA = (const float*)d_in[1];
    const float* bA = (const float*)d_in[2];
    const float* wB = (const float*)d_in[3];
    const float* bB = (const float*)d_in[4];
    const float* wV = (const float*)d_in[5];
    const float* bV = (const float*)d_in[6];
    const float* wR = (const float*)d_in[7];
    const float* bR = (const float*)d_in[8];
    float* out = (float*)d_out;

    const int B = 32;
    const long sY = (long)1536 * 1024;   // per-batch Y stride (bf16 elems)

    // workspace carve-up (~116 MB)
    char* p = (char*)d_ws;
    u16*   Y    = (u16*)p;   p += (long)B * sY * 2;          // 96 MB  [A'; Em; Ev]
    u16*   H    = (u16*)p;   p += (long)B * 512 * 512 * 2;   // 16 MB  H2 [o,d]
    u16*   Wcat = (u16*)p;   p += (long)1536 * 512 * 2;      // [M1;wB;wV]
    u16*   wRb  = (u16*)p;   p += (long)512 * 512 * 2;
    u16*   wAtb = (u16*)p;   p += (long)512 * 512 * 2;       // wA^T bf16
    float* bcat = (float*)p; p += 1536 * 4;
    float* svec = (float*)p; p += (long)B * 1024 * 4;        // colsum of attnV
    float* wRbA = (float*)p; p += 512 * 4;
    float* rspart = (float*)p; p += (long)B * 4096 * 4;      // [B][4][1024] partials

    // Xt (bf16 [b,1024,512], 33.5 MB) lives in d_out — dead before final GEMM
    u16* Xt = (u16*)d_out;
    // Vt reuses Y's A'-region after the H-GEMM consumed A'
    u16* Vt = Y;                        // [1024,512] per batch, stride sY

    // 0. casts + tiny precomputes
    cast_transpose_x<<<dim3(16, 8, B), 256, 0, stream>>>(x, Xt);
    prep_weights<<<dim3(4359), 256, 0, stream>>>(wA, wB, wV, wR, bA, bB, bV,
                                                 Wcat, wRb, wAtb, bcat, wRbA,
                                                 svec);

    // 1. M1 = wR*wA -> Wcat rows 0..511   (NT: A=wRb[512,512], B=wAtb[512,512])
    gemm_nt<128, false, false><<<dim3(4, 4, 1), 256, 0, stream>>>(
        wRb, wAtb, Wcat, nullptr, 512, 512, 0, 0, 0);

    // 2. Y[b] = Wcat * X[b] + bcat; rows 512+ get exp() + rspart partial sums
    gemm2_y<<<dim3(768), 512, 0, stream>>>(Wcat, Xt, Y, bcat, rspart);

    // 3. H2[b][o,d] = (sum_n A'[o,n]*Em[d,n]) / (S_b[d]*S_v[d])
    //    (NT, K=1024; pure async staging; normalizers as column scales)
    gemm_nt_swz<128, false, false, false, true><<<dim3(512), 256, 0, stream>>>(
        Y, Y + (long)512 * 1024, H, nullptr, 512, 1024,
        sY, sY, (long)512 * 512, 4, 16, nullptr, nullptr, rspart);

    // 4. Vt[b] = Ev[b]^T; svec[n] = sum_d Ev[d,n]/S_v[d]  (A'-region dead now)
    transpose_colsum<<<dim3(16, 8, B), 256, 0, stream>>>(
        Y + (long)1024 * 1024, Vt, svec, sY, sY, rspart);

    // 5. out[b][o,n] = sum_d H2[o,d]*Vt[n,d] + wRbA[o]*svec[n] + bR[o] (fp32)
    gemm_nt_swz<128, true, true, true, false><<<dim3(1024), 256, 0, stream>>>(
        H, Vt, out, bR, 1024, 512, (long)512 * 512, sY, (long)512 * 1024,
        8, 32, svec, wRbA, nullptr);
}

// Round 8
// 267.689 us; speedup vs baseline: 1.1235x; 1.0490x over previous
//
#include <hip/hip_runtime.h>
#include <stdint.h>

typedef unsigned short u16;
typedef __bf16  bf16x8 __attribute__((ext_vector_type(8)));
typedef float   f32x4  __attribute__((ext_vector_type(4)));

__device__ __forceinline__ u16 f2bf(float f) {
    union { float f; unsigned u; } c; c.f = f;
    unsigned r = c.u + 0x7fffu + ((c.u >> 16) & 1u);   // RNE, finite inputs
    return (u16)(r >> 16);
}
__device__ __forceinline__ float bf2f(u16 b) {
    union { unsigned u; float f; } c; c.u = ((unsigned)b) << 16; return c.f;
}

// async 16B global->LDS. Generic LDS ptr: low 32 bits are the LDS offset on gfx9+.
__device__ __forceinline__ void g2l16(const u16* g, u16* l) {
    __builtin_amdgcn_global_load_lds(
        (__attribute__((address_space(1))) void*)(uintptr_t)g,
        (__attribute__((address_space(3))) void*)(uint32_t)(uintptr_t)l,
        16, 0, 0);
}

// ---------------------------------------------------------------------------
// NT GEMM core (bf16 in, fp32 acc): C[m,n] = sum_k A[m,k]*B[n,k]
//   (+ bias[m])
//   CSCALE (gemm4): v = acc/(S_b[n]*S_v[n]) + wRbA[m]/S_v[n]  — the rank-1
//     wRbA (x) colsum(attnV) term folded in algebraically (svec = colsum of
//     attnV, so out = (H2 + wRbA*1^T)*attnV; attnM rows sum to 1).
// A,B row-major bf16, ld == K. Tile TM x 128, BK=64, 256 thr = 4 waves (2x2).
// LDS XOR-swizzle: physical 16B chunk = logical ^ (row&7) -> conflict-free.
// ---------------------------------------------------------------------------
template <int TM, bool HAS_BIAS, bool OUT_F32, bool CSCALE>
__device__ __forceinline__ void gemm_core(
    const u16* __restrict__ Ab, const u16* __restrict__ Bb, void* __restrict__ C,
    const float* __restrict__ bias, int N, int K, long cbase, int m0, int n0,
    const float* __restrict__ wRbA,
    const float* __restrict__ rs)   // rspart[4][1024] for this batch
{
    constexpr int MI = TM / 32;
    constexpr int NA = TM / 32;
    __shared__ __align__(16) u16 As[TM * 64];
    __shared__ __align__(16) u16 Bs[128 * 64];

    const int t = threadIdx.x;
    const int w = t >> 6, lane = t & 63;
    const int wr = w >> 1, wc = w & 1;

    f32x4 acc[MI][4];
    const f32x4 zero = {0.f, 0.f, 0.f, 0.f};
#pragma unroll
    for (int i = 0; i < MI; ++i)
#pragma unroll
        for (int j = 0; j < 4; ++j) acc[i][j] = zero;

    int  aslot[NA]; long aoff[NA];
#pragma unroll
    for (int i = 0; i < NA; ++i) {
        const int s   = i * 256 + t;
        const int row = s >> 3;
        const int col = ((s & 7) ^ (row & 7)) * 8;
        aslot[i] = s * 8;
        aoff[i]  = (long)(m0 + row) * K + col;
    }
    int  bslot[4]; long boff[4];
#pragma unroll
    for (int i = 0; i < 4; ++i) {
        const int s   = i * 256 + t;
        const int row = s >> 3;
        const int col = ((s & 7) ^ (row & 7)) * 8;
        bslot[i] = s * 8;
        boff[i]  = (long)(n0 + row) * K + col;
    }

    const int fr = lane & 15;
    const int q  = lane >> 4;
    const int o0 = ((q ^ (fr & 7)) * 8);   // kh=0; kh=1 is o0 ^ 32
    const u16* fa = &As[(wr * (TM / 2) + fr) * 64];
    const u16* fb = &Bs[(wc * 64 + fr) * 64];

    for (int k0 = 0; k0 < K; k0 += 64) {
#pragma unroll
        for (int i = 0; i < NA; ++i) g2l16(Ab + aoff[i] + k0, &As[aslot[i]]);
#pragma unroll
        for (int i = 0; i < 4; ++i)  g2l16(Bb + boff[i] + k0, &Bs[bslot[i]]);
        __syncthreads();

#pragma unroll
        for (int kh = 0; kh < 2; ++kh) {
            const int o = o0 ^ (kh * 32);
            bf16x8 af[MI], bv[4];
#pragma unroll
            for (int mi = 0; mi < MI; ++mi) af[mi] = *(const bf16x8*)(fa + mi * 1024 + o);
#pragma unroll
            for (int ni = 0; ni < 4; ++ni)  bv[ni] = *(const bf16x8*)(fb + ni * 1024 + o);
#pragma unroll
            for (int mi = 0; mi < MI; ++mi)
#pragma unroll
                for (int ni = 0; ni < 4; ++ni)
                    acc[mi][ni] = __builtin_amdgcn_mfma_f32_16x16x32_bf16(
                        af[mi], bv[ni], acc[mi][ni], 0, 0, 0);
        }
        __syncthreads();
    }

    // C/D layout (m89-verified): col = lane&15, row = (lane>>4)*4 + reg
    const int ccol  = n0 + wc * 64 + fr;
    const int crow0 = m0 + wr * (TM / 2) + (lane >> 4) * 4;
    float sc[4], svn[4];
    if (CSCALE) {
#pragma unroll
        for (int ni = 0; ni < 4; ++ni) {
            const int c = ccol + ni * 16;
            const float sb = rs[c]       + rs[1024 + c] + rs[2048 + c] + rs[3072 + c];
            const float sv = rs[512 + c] + rs[1536 + c] + rs[2560 + c] + rs[3584 + c];
            sc[ni]  = 1.0f / (sb * sv);
            svn[ni] = 1.0f / sv;
        }
    }
#pragma unroll
    for (int mi = 0; mi < MI; ++mi) {
#pragma unroll
        for (int r = 0; r < 4; ++r) {
            const int row = crow0 + mi * 16 + r;
            float add = HAS_BIAS ? bias[row] : 0.f;
            float rk  = CSCALE ? wRbA[row] : 0.f;
#pragma unroll
            for (int ni = 0; ni < 4; ++ni) {
                float v = acc[mi][ni][r] + add;
                if (CSCALE) v = v * sc[ni] + rk * svn[ni];
                const long idx = cbase + (long)row * N + ccol + ni * 16;
                if (OUT_F32) ((float*)C)[idx] = v;
                else         ((u16*)C)[idx]   = f2bf(v);
            }
        }
    }
}

// 3D-grid variant (GEMM1): blockIdx = (n-blk, m-blk, batch)
template <int TM, bool HAS_BIAS, bool OUT_F32>
__global__ __launch_bounds__(256) void gemm_nt(
    const u16* __restrict__ A, const u16* __restrict__ B, void* __restrict__ C,
    const float* __restrict__ bias, int N, int K, long sA, long sB, long sC)
{
    const int bz = blockIdx.z;
    gemm_core<TM, HAS_BIAS, OUT_F32, false>(
        A + (long)bz * sA, B + (long)bz * sB, C, bias, N, K,
        (long)bz * sC, blockIdx.y * TM, blockIdx.x * 128, nullptr, nullptr);
}

// 1D-grid XCD-swizzled variant (GEMM4 / GEMM6): batch b lands on XCD b%8
template <int TM, bool HAS_BIAS, bool OUT_F32, bool CSCALE>
__global__ __launch_bounds__(256) void gemm_nt_swz(
    const u16* __restrict__ A, const u16* __restrict__ B, void* __restrict__ C,
    const float* __restrict__ bias, int N, int K, long sA, long sB, long sC,
    int bxn, int bpb, const float* __restrict__ wRbA,
    const float* __restrict__ rs_all)
{
    const int blk  = blockIdx.x;
    const int xcd  = blk & 7;
    const int slot = blk >> 3;
    const int b    = xcd + 8 * (slot / bpb);
    const int wi   = slot % bpb;
    const int bx   = wi % bxn;
    const int by   = wi / bxn;
    gemm_core<TM, HAS_BIAS, OUT_F32, CSCALE>(
        A + (long)b * sA, B + (long)b * sB, C, bias, N, K,
        (long)b * sC, by * TM, bx * 128, wRbA,
        CSCALE ? rs_all + (long)b * 4096 : nullptr);
}

// ---------------------------------------------------------------------------
// GEMM2 (Y = Wcat * Xt^T + bcat), 256x256 tile, 512 thr = 8 waves (2x4),
// BK=32, 4 LDS buffers (128 KiB), 2-tiles-ahead prefetch, counted vmcnt(4),
// batch-colocated XCD map (1D grid 768 = 8 XCD x 96, bijective).
// v8 epilogue: shift-free softmax exp for rows >= 512 (fp32 on accumulators);
// per-row partial sums -> rspart via shfl+LDS+plain store (R7, no atomics).
// NEW: Vm blocks (m0 >= 1024) write exp(v) DIRECTLY TRANSPOSED into the Vt
// region (Y rows 1024..1535 reinterpreted as [n][d], ushort4 along d; a
// wave's stores cover 16 n-rows x 32B chunks that L2 merges into full
// lines). Values bit-identical to R7's transpose_colsum output — the whole
// transpose kernel is deleted, and the svec colsum is folded into gemm4's
// epilogue (see gemm_core CSCALE).
// ---------------------------------------------------------------------------
__global__ __launch_bounds__(512) void gemm2_y(
    const u16* __restrict__ A,      // Wcat [1536,512]
    const u16* __restrict__ B,      // Xt   [b][1024,512]
    u16* __restrict__ C,            // Y    [b][1536,1024]
    const float* __restrict__ bias, // bcat [1536]
    float* __restrict__ rspart)     // [B][4][1024] partial exp-rowsums
{
    constexpr int K    = 512;
    constexpr int NT   = K / 32;          // 16 K-tiles
    constexpr int AREG = 256 * 32;        // u16 per operand region (8192)
    constexpr int BUFQ = 2 * AREG;        // u16 per buffer (A+B)
    __shared__ __align__(16) u16 lds[4 * BUFQ];   // 128 KiB

    const int blk  = blockIdx.x;
    const int xcd  = blk & 7;
    const int slot = blk >> 3;
    const int bz   = xcd + 8 * (slot / 24);
    const int wi   = slot % 24;
    const int m0   = (wi >> 2) * 256;     // 6 m-blocks
    const int n0   = (wi & 3) * 256;      // 4 n-blocks

    const u16* Ab = A;
    const u16* Bb = B + (long)bz * (1024 * 512);
    u16*       Cb = C + (long)bz * ((long)1536 * 1024);

    const int t    = threadIdx.x;
    const int w    = t >> 6, lane = t & 63;
    const int wr   = w >> 2, wc = w & 3;          // wave grid 2(M) x 4(N)
    const int fr   = lane & 15, q = lane >> 4;

    // ---- staging map: 1024 16B-chunks per operand per K-tile; 2/thread ----
    int  aslot[2]; long agoff[2], bgoff[2];
#pragma unroll
    for (int i = 0; i < 2; ++i) {
        const int ci  = i * 512 + t;
        const int row = ci >> 2;
        const int gc  = (ci & 3) ^ ((row >> 1) & 3);   // inverse == forward (XOR)
        aslot[i] = ci * 8;                             // linear u16 LDS slot
        agoff[i] = (long)(m0 + row) * K + gc * 8;
        bgoff[i] = (long)(n0 + row) * K + gc * 8;
    }

    // ---- fragment read offsets (u16): row*32 + chunk*8 ----
    const int rchunk = (q ^ ((fr >> 1) & 3)) * 8;
    const int abase  = (wr * 128 + fr) * 32 + rchunk;   // + mi*512
    const int bbase  = (wc * 64  + fr) * 32 + rchunk;   // + ni*512

    f32x4 acc[8][4];
    const f32x4 zero = {0.f, 0.f, 0.f, 0.f};
#pragma unroll
    for (int i = 0; i < 8; ++i)
#pragma unroll
        for (int j = 0; j < 4; ++j) acc[i][j] = zero;

    // ---- prologue: stage tiles 0 and 1 (A0,B0,A1,B1 -> 8 loads/thread) ----
#pragma unroll
    for (int i = 0; i < 2; ++i) g2l16(Ab + agoff[i],        &lds[aslot[i]]);
#pragma unroll
    for (int i = 0; i < 2; ++i) g2l16(Bb + bgoff[i],        &lds[AREG + aslot[i]]);
#pragma unroll
    for (int i = 0; i < 2; ++i) g2l16(Ab + agoff[i] + 32,   &lds[BUFQ + aslot[i]]);
#pragma unroll
    for (int i = 0; i < 2; ++i) g2l16(Bb + bgoff[i] + 32,   &lds[BUFQ + AREG + aslot[i]]);
    asm volatile("s_waitcnt vmcnt(4)" ::: "memory");   // tile 0 landed; tile 1 in flight
    __builtin_amdgcn_s_barrier();
    asm volatile("" ::: "memory");                     // no hoists above barrier

#pragma unroll
    for (int kt = 0; kt < NT; ++kt) {
        const u16* Abuf = &lds[(kt & 3) * BUFQ];           // constexpr (unrolled)
        const u16* Bbuf = Abuf + AREG;
        u16* dst = &lds[((kt + 2) & 3) * BUFQ];
        const long kg = (long)(kt + 2) * 32;

        // ---- fat region: reads + stage + MFMA, compiler-scheduled ----
        bf16x8 av[8], bv[4];
#pragma unroll
        for (int mi = 0; mi < 8; ++mi) av[mi] = *(const bf16x8*)(Abuf + abase + mi * 512);
#pragma unroll
        for (int ni = 0; ni < 4; ++ni) bv[ni] = *(const bf16x8*)(Bbuf + bbase + ni * 512);
        if (kt + 2 < NT) {                                 // constexpr (unrolled)
#pragma unroll
            for (int i = 0; i < 2; ++i) g2l16(Ab + agoff[i] + kg, dst + aslot[i]);
#pragma unroll
            for (int i = 0; i < 2; ++i) g2l16(Bb + bgoff[i] + kg, dst + AREG + aslot[i]);
        }
#pragma unroll
        for (int mi = 0; mi < 8; ++mi)
#pragma unroll
            for (int ni = 0; ni < 4; ++ni)
                acc[mi][ni] = __builtin_amdgcn_mfma_f32_16x16x32_bf16(
                    av[mi], bv[ni], acc[mi][ni], 0, 0, 0);

        // ---- tile boundary: counted wait (tile kt+1 landed; kt+2 in flight) ----
        if (kt + 1 < NT) {
            if (kt + 2 < NT) asm volatile("s_waitcnt vmcnt(4)" ::: "memory");
            else             asm volatile("s_waitcnt vmcnt(0)" ::: "memory");
            __builtin_amdgcn_s_barrier();
            asm volatile("" ::: "memory");                 // no hoists above barrier
        }
    }

    // ---- epilogue: col = lane&15, row = (lane>>4)*4 + reg ----
    const int ccol  = n0 + wc * 64 + fr;
    const int crow0 = m0 + wr * 128 + q * 4;
    const bool sm = (m0 >= 512);
    const bool tr = (m0 >= 1024);
    float rsums[8][4];
    if (!tr) {
#pragma unroll
        for (int mi = 0; mi < 8; ++mi) {
#pragma unroll
            for (int r = 0; r < 4; ++r) {
                const int row = crow0 + mi * 16 + r;
                const float add = bias[row];
                float rsum = 0.f;
#pragma unroll
                for (int ni = 0; ni < 4; ++ni) {
                    float v = acc[mi][ni][r] + add;
                    if (sm) { v = __expf(v); rsum += v; }
                    Cb[(long)row * 1024 + ccol + ni * 16] = f2bf(v);
                }
                rsums[mi][r] = rsum;
            }
        }
    } else {
        // Vm blocks: exp(v) written TRANSPOSED into Vt = Y rows 1024+ as
        // [n][d] (ushort4 along d; r-index IS the d offset).
        u16* Vtb = Cb + (long)1024 * 1024;
#pragma unroll
        for (int mi = 0; mi < 8; ++mi) {
            const int growr = crow0 + mi * 16;   // global Y row (r=0)
            const int d0    = growr - 1024;      // d base (mult of 4 -> 8B aligned)
#pragma unroll
            for (int r = 0; r < 4; ++r) rsums[mi][r] = 0.f;
#pragma unroll
            for (int ni = 0; ni < 4; ++ni) {
                const int n = ccol + ni * 16;
                ushort4 o4;
                float e;
                e = __expf(acc[mi][ni][0] + bias[growr + 0]); rsums[mi][0] += e; o4.x = f2bf(e);
                e = __expf(acc[mi][ni][1] + bias[growr + 1]); rsums[mi][1] += e; o4.y = f2bf(e);
                e = __expf(acc[mi][ni][2] + bias[growr + 2]); rsums[mi][2] += e; o4.z = f2bf(e);
                e = __expf(acc[mi][ni][3] + bias[growr + 3]); rsums[mi][3] += e; o4.w = f2bf(e);
                *(ushort4*)&Vtb[(long)n * 512 + d0] = o4;
            }
        }
    }
    if (sm) {   // uniform branch (m0 is block-uniform)
        // reduce over the 16 fr lanes -> fr==0 holds this wave's 64-col sum
#pragma unroll
        for (int mi = 0; mi < 8; ++mi)
#pragma unroll
            for (int r = 0; r < 4; ++r) {
                float v = rsums[mi][r];
                v += __shfl_xor(v, 1);
                v += __shfl_xor(v, 2);
                v += __shfl_xor(v, 4);
                v += __shfl_xor(v, 8);
                rsums[mi][r] = v;
            }
        __syncthreads();                 // all LDS reads of the K-loop done
        float* lsc = (float*)lds;        // scratch: [2][128][4] (wr, lrow, wc)
        if (fr == 0) {
#pragma unroll
            for (int mi = 0; mi < 8; ++mi)
#pragma unroll
                for (int r = 0; r < 4; ++r) {
                    const int lrow = mi * 16 + q * 4 + r;          // 0..127
                    lsc[(wr * 128 + lrow) * 4 + wc] = rsums[mi][r];
                }
        }
        __syncthreads();
        if (t < 256) {
            const f32x4 pv = *(const f32x4*)&lsc[t * 4];
            const int grow = (m0 - 512) + t;                       // 0..1023
            rspart[((long)bz * 4 + (n0 >> 8)) * 1024 + grow] =
                pv[0] + pv[1] + pv[2] + pv[3];
        }
    }
}

// ---------------------------------------------------------------------------
// fused_pre = cast_transpose_x (blocks 0..4095) + weight casts (4096..8198)
//           + wRbA (8199..8326), one launch. ctx and prep are independent;
//           ctx blocks dispatch first (they carry the 160 MB of traffic).
// ---------------------------------------------------------------------------
__global__ __launch_bounds__(256) void fused_pre(
    const float* __restrict__ in, u16* __restrict__ out,   // ctx: x -> Xt
    const float* __restrict__ wA, const float* __restrict__ wB,
    const float* __restrict__ wV, const float* __restrict__ wR,
    const float* __restrict__ bA, const float* __restrict__ bB,
    const float* __restrict__ bV,
    u16* __restrict__ Wcat, u16* __restrict__ wRb, u16* __restrict__ wAtb,
    float* __restrict__ bcat, float* __restrict__ wRbA)
{
    __shared__ u16 tile[64][68];
    const int blk = blockIdx.x;
    if (blk < 4096) {
        // ---- cast + transpose x [512,1024] fp32 -> Xt [1024,512] bf16 ----
        const int bz  = blk >> 7;
        const int rem = blk & 127;
        const int c0  = (rem & 15) * 64;
        const int r0  = (rem >> 4) * 64;
        const float* ip = in  + (long)bz * (512 * 1024);
        u16*         op = out + (long)bz * (1024 * 512);
        const int tx = threadIdx.x & 15;
        const int ty = threadIdx.x >> 4;
#pragma unroll
        for (int p = 0; p < 4; ++p) {
            const int row = ty + 16 * p;
            float4 v = *(const float4*)(ip + (long)(r0 + row) * 1024 + c0 + 4 * tx);
            ushort4 o;
            o.x = f2bf(v.x); o.y = f2bf(v.y); o.z = f2bf(v.z); o.w = f2bf(v.w);
            *(ushort4*)&tile[row][4 * tx] = o;
        }
        __syncthreads();
#pragma unroll
        for (int p = 0; p < 4; ++p) {
            const int orow = ty + 16 * p;
            ushort4 o;
            o.x = tile[4 * tx + 0][orow];
            o.y = tile[4 * tx + 1][orow];
            o.z = tile[4 * tx + 2][orow];
            o.w = tile[4 * tx + 3][orow];
            *(ushort4*)&op[(long)(c0 + orow) * 512 + r0 + 4 * tx] = o;
        }
    } else if (blk < 4096 + 4103) {
        const int tid = (blk - 4096) * 256 + threadIdx.x;
        if (tid < 262144) {
            Wcat[262144 + tid] = f2bf(wB[tid]);                    // rows 512..1023
        } else if (tid < 524288) {
            Wcat[262144 + tid] = f2bf(wV[tid - 262144]);           // rows 1024..1535
        } else if (tid < 786432) {
            wRb[tid - 524288] = f2bf(wR[tid - 524288]);
        } else if (tid < 1048576) {
            const int i = tid - 786432;                            // i = c*512 + cin
            wAtb[(i & 511) * 512 + (i >> 9)] = f2bf(wA[i]);        // wA^T
        } else if (tid < 1048576 + 1536) {
            const int j = tid - 1048576;
            bcat[j] = (j < 512) ? 0.f : (j < 1024) ? bB[j - 512] : bV[j - 1024];
        }
    } else {
        const int o    = (blk - (4096 + 4103)) * 4 + (threadIdx.x >> 6);
        const int lane = threadIdx.x & 63;
        float a = 0.f;
#pragma unroll
        for (int c = lane; c < 512; c += 64) a += wR[o * 512 + c] * bA[c];
#pragma unroll
        for (int off = 32; off > 0; off >>= 1) a += __shfl_down(a, off);
        if (lane == 0) wRbA[o] = a;
    }
}

// ---------------------------------------------------------------------------
extern "C" void kernel_launch(void* const* d_in, const int* in_sizes, int n_in,
                              void* d_out, int out_size, void* d_ws, size_t ws_size,
                              hipStream_t stream)
{
    (void)in_sizes; (void)n_in; (void)out_size; (void)ws_size;
    const float* x  = (const float*)d_in[0];
    const float* wA = (const float*)d_in[1];
    const float* bA = (const float*)d_in[2];
    const float* wB = (const float*)d_in[3];
    const float* bB = (const float*)d_in[4];
    const float* wV = (const float*)d_in[5];
    const float* bV = (const float*)d_in[6];
    const float* wR = (const float*)d_in[7];
    const float* bR = (const float*)d_in[8];
    float* out = (float*)d_out;

    const int B = 32;
    const long sY = (long)1536 * 1024;   // per-batch Y stride (bf16 elems)

    // workspace carve-up (~115 MB)
    char* p = (char*)d_ws;
    u16*   Y    = (u16*)p;   p += (long)B * sY * 2;          // 96 MB  [A'; Em; Vt]
    u16*   H    = (u16*)p;   p += (long)B * 512 * 512 * 2;   // 16 MB  H3 [o,d]
    u16*   Wcat = (u16*)p;   p += (long)1536 * 512 * 2;      // [M1;wB;wV]
    u16*   wRb  = (u16*)p;   p += (long)512 * 512 * 2;
    u16*   wAtb = (u16*)p;   p += (long)512 * 512 * 2;       // wA^T bf16
    float* bcat = (float*)p; p += 1536 * 4;
    float* wRbA = (float*)p; p += 512 * 4;
    float* rspart = (float*)p; p += (long)B * 4096 * 4;      // [B][4][1024] partials

    // Xt (bf16 [b,1024,512], 33.5 MB) lives in d_out — dead before final GEMM
    u16* Xt = (u16*)d_out;

    // 0. x cast/transpose + weight prep, one launch (independent paths)
    fused_pre<<<dim3(8327), 256, 0, stream>>>(x, Xt, wA, wB, wV, wR, bA, bB, bV,
                                              Wcat, wRb, wAtb, bcat, wRbA);

    // 1. M1 = wR*wA -> Wcat rows 0..511   (NT: A=wRb[512,512], B=wAtb[512,512])
    gemm_nt<128, false, false><<<dim3(4, 4, 1), 256, 0, stream>>>(
        wRb, wAtb, Wcat, nullptr, 512, 512, 0, 0, 0);

    // 2. Y[b] = Wcat * X[b] + bcat; Em rows exp'd in place; Vm rows exp'd and
    //    written TRANSPOSED as Vt; rspart partial row sums
    gemm2_y<<<dim3(768), 512, 0, stream>>>(Wcat, Xt, Y, bcat, rspart);

    // 3. H3[b][o,d] = (sum_n A'[o,n]*Em[d,n])/(S_b[d]*S_v[d]) + wRbA[o]/S_v[d]
    //    (rank-1 svec term folded in: out = (H2 + wRbA*1^T)*attnV + bR)
    gemm_nt_swz<128, false, false, true><<<dim3(512), 256, 0, stream>>>(
        Y, Y + (long)512 * 1024, H, nullptr, 512, 1024,
        sY, sY, (long)512 * 512, 4, 16, wRbA, rspart);

    // 4. out[b][o,n] = sum_d H3[o,d]*Vt[n,d] + bR[o]  (fp32 out)
    gemm_nt_swz<128, true, true, false><<<dim3(1024), 256, 0, stream>>>(
        H, Y + (long)1024 * 1024, out, bR, 1024, 512,
        (long)512 * 512, sY, (long)512 * 1024, 8, 32, nullptr, nullptr);
}